// Round 16
// baseline (170.744 us; speedup 1.0000x reference)
//
#include <hip/hip_runtime.h>
#include <stdint.h>

#define NBOX 8000
#define NPAD 8192
#define NBLK 256                             // mask_nms grid: 128 words x 2 halves
#define ECAP 16384                           // LDS edge cache (64 KB)

// ---- workspace layout (bytes) ----
#define ECNT_OFF 0                           // u32 edge count  (zeroed by sort_decode)
#define DONE_OFF 4                           // u32 done blocks (zeroed by sort_decode)
#define SB(i)    (0x10000 + (size_t)(i) * 0x8000)
// sorted-by-rank arrays (float[8192] each):
// 0 bx, 1 by, 2 bw, 3 bh, 4 conf, 5 cls, 6 x1, 7 y1, 8 x2, 9 y2, 10 area
#define EDGE_OFF (size_t)0x200000            // u32 edges (i<<13|j); max 134MB < ws

__device__ __forceinline__ float sigmoidf_(float x) {
    return 1.0f / (1.0f + expf(-x));
}

// ---------------- fused decode + rank + scatter-to-sorted ----------------
// Block b owns source boxes [b*64, b*64+64).
// Phase 1: 512 threads materialize ALL 8192 keys into LDS once. ONE barrier.
// Phase 2: wave w ranks the block's 64 row-keys against key segment
//          [w*1024,(w+1)*1024): broadcast LDS reads, zero barriers.
// Phase 3: wave 0 sums partials, fully decodes its 64 CONSECUTIVE boxes
//          (coalesced loads; only rank-indexed stores scatter).
// Validity downstream = sconf[r] > 0.5 (sorted => equivalent to r < V).
__global__ __launch_bounds__(512) void sort_decode_kernel(const float* __restrict__ x,
                                                          const float* __restrict__ anchors,
                                                          unsigned char* __restrict__ ws) {
    __shared__ unsigned long long keys[NPAD];    // 64 KB
    __shared__ int partial[512];
    int tid  = threadIdx.x;
    int lane = tid & 63;
    int wv   = tid >> 6;                         // wave 0..7
    int b    = blockIdx.x;                       // 128 blocks

    if (b == 0 && tid == 0)
        *(unsigned long long*)(ws + ECNT_OFF) = 0ull;   // zero ECNT + DONE

    // ---- phase 1: all keys -> LDS (16 coalesced loads/thread) ----
    for (int t = tid; t < NPAD; t += 512) {
        unsigned long long k;
        if (t < NBOX) {
            int a = t / 1600, pos = t - a * 1600;
            float c = sigmoidf_(x[a * 40000 + 4 * 1600 + pos]);
            k = ((unsigned long long)__float_as_uint(c) << 32) | (unsigned long long)(8191 - t);
        } else {
            k = (unsigned long long)(8191 - t);  // pads sort last (conf bits = 0)
        }
        keys[t] = k;
    }
    __syncthreads();

    // ---- phase 2: rank; wave wv vs segment wv (broadcast LDS reads) ----
    int i = (b << 6) + lane;                     // source box owned by this lane
    unsigned long long ki = keys[i];
    const unsigned long long* ks = &keys[wv << 10];
    int cnt = 0;
    #pragma unroll 8
    for (int jj = 0; jj < 1024; ++jj) cnt += (ks[jj] > ki) ? 1 : 0;
    partial[(wv << 6) + lane] = cnt;
    __syncthreads();

    // ---- phase 3: wave 0 sums partials, decodes, scatter-writes ----
    if (wv == 0) {
        int r = 0;
        #pragma unroll
        for (int s = 0; s < 8; ++s) r += partial[(s << 6) + lane];

        float bx = 0.f, by = 0.f, bw = 0.f, bh = 0.f, conf = 0.f, cls = -1.0f;
        if (i < NBOX) {                          // full decode (coalesced channel loads)
            int a = i / 1600, pos = i - a * 1600;
            int gy = pos / 40, gx = pos - gy * 40;
            const float* p = x + (size_t)a * 40000 + pos;
            float tx = sigmoidf_(p[0]);
            float ty = sigmoidf_(p[1600]);
            float tw = p[2 * 1600];
            float th = p[3 * 1600];
            conf = sigmoidf_(p[4 * 1600]);
            float best = -1.0f; int bi = 0;
            #pragma unroll
            for (int c = 0; c < 20; ++c) {       // first-max wins, matches jnp.argmax
                float v = sigmoidf_(p[(5 + c) * 1600]);
                if (v > best) { best = v; bi = c; }
            }
            float aw = anchors[a * 2 + 0];
            float ah = anchors[a * 2 + 1];
            bx = (tx + (float)gx) * 8.0f;
            by = (ty + (float)gy) * 8.0f;
            bw = expf(tw) * aw * 8.0f;
            bh = expf(th) * ah * 8.0f;
            cls = (float)bi;
        }
        {
        #pragma clang fp contract(off)
            float x1 = bx - bw / 2.0f, y1 = by - bh / 2.0f;
            float x2 = bx + bw / 2.0f, y2 = by + bh / 2.0f;
            float ar = fabsf((x2 - x1) * (y2 - y1));   // ref: recomputed from corners
            ((float*)(ws + SB(0)))[r]  = bx;  ((float*)(ws + SB(1)))[r]  = by;
            ((float*)(ws + SB(2)))[r]  = bw;  ((float*)(ws + SB(3)))[r]  = bh;
            ((float*)(ws + SB(4)))[r]  = conf; ((float*)(ws + SB(5)))[r] = cls;
            ((float*)(ws + SB(6)))[r]  = x1;  ((float*)(ws + SB(7)))[r]  = y1;
            ((float*)(ws + SB(8)))[r]  = x2;  ((float*)(ws + SB(9)))[r]  = y2;
            ((float*)(ws + SB(10)))[r] = ar;
        }
    }
}

// ---------------- fused mask + last-block Jacobi NMS + output ----------------
// Grid 128 words x 2 halves, 1024 threads; thread covers 4 rows (64-col LDS
// tile reused). 256 blocks = 1/CU, so the 64KB eshare cache costs NO
// occupancy (R14's mistake was 1024 blocks -> 2 scheduling rounds).
// Completion: __syncthreads (drain edge stores) -> tid0 agent release fence +
// ACQ_REL fetch_add; the block seeing old==NBLK-1 acquires, copies edges to
// LDS ONCE, and runs the Jacobi fixed point
//   a[j] = valid[j] & ~OR_{i<j,edge} a[i]   (== greedy NMS, unique FP)
// with DOUBLE-BUFFERED supp (2 barriers/iter; update phase zeroes the other
// buffer) until exact convergence, then writes the output.
__global__ __launch_bounds__(1024) void mask_nms_kernel(unsigned char* __restrict__ ws,
                                                        float* __restrict__ out) {
#pragma clang fp contract(off)
    __shared__ float cx1[64], cy1[64], cx2[64], cy2[64], car[64], ccl[64], ccf[64];
    __shared__ unsigned int eshare[ECAP];          // 64 KB edge cache (elected block only)
    __shared__ unsigned long long valid[128], alive[128], sA[128], sB[128];
    __shared__ int flag, isLast;

    const float* sconf = (const float*)(ws + SB(4));
    int tid  = threadIdx.x;
    int lane = tid & 63;
    int w  = blockIdx.x;                           // word 0..127
    int h  = blockIdx.y;                           // half 0..1
    int j0 = w << 6;
    int ibase = h << 12;                           // 4096-row range

    if (sconf[j0] > 0.5f) {                        // word has any valid col (sorted)
        const float* sx1 = (const float*)(ws + SB(6));
        const float* sy1 = (const float*)(ws + SB(7));
        const float* sx2 = (const float*)(ws + SB(8));
        const float* sy2 = (const float*)(ws + SB(9));
        const float* sar = (const float*)(ws + SB(10));
        const float* scl = (const float*)(ws + SB(5));
        if (tid < 64) {
            int j = j0 + tid;
            cx1[tid] = sx1[j]; cy1[tid] = sy1[j];
            cx2[tid] = sx2[j]; cy2[tid] = sy2[j];
            car[tid] = sar[j]; ccl[tid] = scl[j]; ccf[tid] = sconf[j];
        }
        __syncthreads();

        unsigned int* edges = (unsigned int*)(ws + EDGE_OFF);
        #pragma unroll
        for (int k = 0; k < 4; ++k) {
            int i0k = ibase + (k << 10);
            if (j0 + 64 <= i0k) continue;          // sub-diagonal sub-tile (uniform)
            int i = i0k + tid;

            unsigned long long word = 0;
            if (sconf[i] > 0.5f && j0 + 64 > i + 1) {   // row valid & not sub-diag
                float x1i = sx1[i], y1i = sy1[i], x2i = sx2[i], y2i = sy2[i];
                float ai = sar[i], ci = scl[i];
                for (int jj = 0; jj < 64; ++jj) {
                    int j = j0 + jj;
                    if (j <= i) continue;
                    if (ccf[jj] <= 0.5f) continue;      // col invalid (== j >= V)
                    if (ccl[jj] != ci) continue;
                    float iw = fminf(x2i, cx2[jj]) - fmaxf(x1i, cx1[jj]);
                    iw = fmaxf(iw, 0.0f);
                    float ih = fminf(y2i, cy2[jj]) - fmaxf(y1i, cy1[jj]);
                    ih = fmaxf(ih, 0.0f);
                    float inter = iw * ih;
                    float denom = ai + car[jj] - inter + 1e-6f;  // ((ai+aj)-inter)+eps, L-to-R
                    if (inter / denom >= 0.5f) word |= (1ull << jj);
                }
            }

            // wave-aggregated edge emission
            int pc = __popcll(word);
            int scan = pc;
            #pragma unroll
            for (int d = 1; d < 64; d <<= 1) {
                int t = __shfl_up(scan, d, 64);
                if (lane >= d) scan += t;
            }
            int total = __shfl(scan, 63, 64);
            if (total > 0) {
                unsigned int base = 0;
                if (lane == 63)
                    base = atomicAdd((unsigned int*)(ws + ECNT_OFF), (unsigned int)total);
                base = (unsigned int)__shfl((int)base, 63, 64);
                unsigned int off = base + (unsigned int)(scan - pc);
                unsigned long long t = word;
                while (t) {
                    int bit = __builtin_ctzll(t);
                    t &= t - 1ull;
                    edges[off++] = ((unsigned int)i << 13) | (unsigned int)(j0 + bit);
                }
            }
        }
    }

    // ---- completion protocol ----
    __syncthreads();                               // drain ALL waves' edge stores
    if (tid == 0) {
        __threadfence();                           // agent release: write back L2
        unsigned int old = __hip_atomic_fetch_add((unsigned int*)(ws + DONE_OFF), 1u,
                                                  __ATOMIC_ACQ_REL, __HIP_MEMORY_SCOPE_AGENT);
        isLast = (old == (NBLK - 1));
    }
    __syncthreads();
    if (!isLast) return;
    __threadfence();                               // acquire: invalidate stale lines

    // ---- Jacobi fixed-point NMS (edges LDS-cached, double-buffered supp) ----
    unsigned int E = *(volatile unsigned int*)(ws + ECNT_OFF);
    const unsigned int* gedges = (const unsigned int*)(ws + EDGE_OFF);

    for (int c = tid >> 6; c < 128; c += 16) {     // valid bitmap from sorted conf
        unsigned long long m = __ballot(sconf[(c << 6) + lane] > 0.5f);
        if (lane == 0) valid[c] = m;
    }
    bool inl = (E <= (unsigned int)ECAP);
    if (inl) for (unsigned int e = tid; e < E; e += 1024) eshare[e] = gedges[e];
    if (tid < 128) { sA[tid] = 0ull; sB[tid] = 0ull; }
    __syncthreads();
    if (tid < 128) alive[tid] = valid[tid];
    __syncthreads();

    int cur = 0;
    for (;;) {
        unsigned long long* sCur = cur ? sB : sA;
        unsigned long long* sNxt = cur ? sA : sB;
        if (tid == 0) flag = 0;
        for (unsigned int e = tid; e < E; e += 1024) {      // scatter into sCur
            unsigned int u = inl ? eshare[e] : gedges[e];
            unsigned int i = u >> 13, j = u & 8191u;
            if ((alive[i >> 6] >> (i & 63)) & 1ull)
                atomicOr(&sCur[j >> 6], 1ull << (j & 63));
        }
        __syncthreads();
        if (tid < 128) {                                    // update + zero other buffer
            unsigned long long na = valid[tid] & ~sCur[tid];
            if (na != alive[tid]) { alive[tid] = na; flag = 1; }
            sNxt[tid] = 0ull;
        }
        __syncthreads();
        if (!flag) break;
        cur ^= 1;
    }

    // ---- fused output: kept ranks get sorted box values, else zero ----
    for (int r = tid; r < NBOX; r += 1024) {
        bool keep = (alive[r >> 6] >> (r & 63)) & 1ull;
        float o0 = 0.f, o1 = 0.f, o2 = 0.f, o3 = 0.f, o4 = 0.f, o5 = 0.f;
        if (keep) {
            o0 = ((const float*)(ws + SB(0)))[r];
            o1 = ((const float*)(ws + SB(1)))[r];
            o2 = ((const float*)(ws + SB(2)))[r];
            o3 = ((const float*)(ws + SB(3)))[r];
            o4 = ((const float*)(ws + SB(4)))[r];
            o5 = ((const float*)(ws + SB(5)))[r];
        }
        out[r * 6 + 0] = o0;
        out[r * 6 + 1] = o1;
        out[r * 6 + 2] = o2;
        out[r * 6 + 3] = o3;
        out[r * 6 + 4] = o4;
        out[r * 6 + 5] = o5;
    }
}

extern "C" void kernel_launch(void* const* d_in, const int* in_sizes, int n_in,
                              void* d_out, int out_size, void* d_ws, size_t ws_size,
                              hipStream_t stream) {
    const float* x       = (const float*)d_in[0];
    const float* anchors = (const float*)d_in[1];
    float* out           = (float*)d_out;
    unsigned char* ws    = (unsigned char*)d_ws;

    sort_decode_kernel<<<NPAD / 64, 512, 0, stream>>>(x, anchors, ws);
    dim3 mgrid(128, 2);
    mask_nms_kernel<<<mgrid, 1024, 0, stream>>>(ws, out);
}

// Round 17
// 128.730 us; speedup vs baseline: 1.3264x; 1.3264x over previous
//
#include <hip/hip_runtime.h>
#include <stdint.h>

#define NBOX 8000
#define NPAD 8192
#define ECAP 16384                           // register/LDS edge path cap
#define SEGW 8                               // words per segment (512 rows)
#define NSEG 16                              // 16 segments x 512 rows = 8192

// ---- workspace layout (bytes) ----
#define ECNT_OFF 0                           // u32 edge count (zeroed by sort_decode)
#define SB(i)    (0x10000 + (size_t)(i) * 0x8000)
// sorted-by-rank arrays (float[8192] each):
// 0 bx, 1 by, 2 bw, 3 bh, 4 conf, 5 cls, 6 x1, 7 y1, 8 x2, 9 y2, 10 area
#define EDGE_OFF (size_t)0x200000            // u32 edges (i<<13|j)

__device__ __forceinline__ float sigmoidf_(float x) {
    return 1.0f / (1.0f + expf(-x));
}

// ---------------- fused decode + rank + scatter-to-sorted (R12, unchanged) ----------------
__global__ __launch_bounds__(512) void sort_decode_kernel(const float* __restrict__ x,
                                                          const float* __restrict__ anchors,
                                                          unsigned char* __restrict__ ws) {
    __shared__ unsigned long long keys[NPAD];    // 64 KB
    __shared__ int partial[512];
    int tid  = threadIdx.x;
    int lane = tid & 63;
    int wv   = tid >> 6;                         // wave 0..7
    int b    = blockIdx.x;                       // 128 blocks

    if (b == 0 && tid == 0) *(unsigned int*)(ws + ECNT_OFF) = 0u;

    // ---- phase 1: all keys -> LDS (coalesced conf loads) ----
    for (int t = tid; t < NPAD; t += 512) {
        unsigned long long k;
        if (t < NBOX) {
            int a = t / 1600, pos = t - a * 1600;
            float c = sigmoidf_(x[a * 40000 + 4 * 1600 + pos]);
            k = ((unsigned long long)__float_as_uint(c) << 32) | (unsigned long long)(8191 - t);
        } else {
            k = (unsigned long long)(8191 - t);  // pads sort last (conf bits = 0)
        }
        keys[t] = k;
    }
    __syncthreads();

    // ---- phase 2: rank; wave wv vs segment wv (broadcast LDS reads) ----
    int i = (b << 6) + lane;                     // source box owned by this lane
    unsigned long long ki = keys[i];
    const unsigned long long* ks = &keys[wv << 10];
    int cnt = 0;
    #pragma unroll 8
    for (int jj = 0; jj < 1024; ++jj) cnt += (ks[jj] > ki) ? 1 : 0;
    partial[(wv << 6) + lane] = cnt;
    __syncthreads();

    // ---- phase 3: wave 0 sums partials, decodes, scatter-writes ----
    if (wv == 0) {
        int r = 0;
        #pragma unroll
        for (int s = 0; s < 8; ++s) r += partial[(s << 6) + lane];

        float bx = 0.f, by = 0.f, bw = 0.f, bh = 0.f, conf = 0.f, cls = -1.0f;
        if (i < NBOX) {                          // full decode (coalesced channel loads)
            int a = i / 1600, pos = i - a * 1600;
            int gy = pos / 40, gx = pos - gy * 40;
            const float* p = x + (size_t)a * 40000 + pos;
            float tx = sigmoidf_(p[0]);
            float ty = sigmoidf_(p[1600]);
            float tw = p[2 * 1600];
            float th = p[3 * 1600];
            conf = sigmoidf_(p[4 * 1600]);
            float best = -1.0f; int bi = 0;
            #pragma unroll
            for (int c = 0; c < 20; ++c) {       // first-max wins, matches jnp.argmax
                float v = sigmoidf_(p[(5 + c) * 1600]);
                if (v > best) { best = v; bi = c; }
            }
            float aw = anchors[a * 2 + 0];
            float ah = anchors[a * 2 + 1];
            bx = (tx + (float)gx) * 8.0f;
            by = (ty + (float)gy) * 8.0f;
            bw = expf(tw) * aw * 8.0f;
            bh = expf(th) * ah * 8.0f;
            cls = (float)bi;
        }
        {
        #pragma clang fp contract(off)
            float x1 = bx - bw / 2.0f, y1 = by - bh / 2.0f;
            float x2 = bx + bw / 2.0f, y2 = by + bh / 2.0f;
            float ar = fabsf((x2 - x1) * (y2 - y1));   // ref: recomputed from corners
            ((float*)(ws + SB(0)))[r]  = bx;  ((float*)(ws + SB(1)))[r]  = by;
            ((float*)(ws + SB(2)))[r]  = bw;  ((float*)(ws + SB(3)))[r]  = bh;
            ((float*)(ws + SB(4)))[r]  = conf; ((float*)(ws + SB(5)))[r] = cls;
            ((float*)(ws + SB(6)))[r]  = x1;  ((float*)(ws + SB(7)))[r]  = y1;
            ((float*)(ws + SB(8)))[r]  = x2;  ((float*)(ws + SB(9)))[r]  = y2;
            ((float*)(ws + SB(10)))[r] = ar;
        }
    }
}

// ---------------- suppression edges (R12 structure, unchanged math) ----------------
__global__ __launch_bounds__(256) void mask_kernel(unsigned char* __restrict__ ws) {
#pragma clang fp contract(off)
    const float* sconf = (const float*)(ws + SB(4));
    int i0 = blockIdx.y * 256;
    int w  = blockIdx.x;
    int j0 = w * 64;
    if (sconf[i0] <= 0.5f) return;                 // whole i-tile invalid (sorted)
    if (sconf[j0] <= 0.5f) return;                 // whole j-word invalid
    if (j0 + 64 <= i0) return;                     // strictly sub-diagonal: empty
    int tid  = threadIdx.x;
    int lane = tid & 63;
    int i    = i0 + tid;

    const float* sx1 = (const float*)(ws + SB(6));
    const float* sy1 = (const float*)(ws + SB(7));
    const float* sx2 = (const float*)(ws + SB(8));
    const float* sy2 = (const float*)(ws + SB(9));
    const float* sar = (const float*)(ws + SB(10));
    const float* scl = (const float*)(ws + SB(5));

    __shared__ float cx1[64], cy1[64], cx2[64], cy2[64], car[64], ccl[64], ccf[64];
    if (tid < 64) {
        int j = j0 + tid;
        cx1[tid] = sx1[j]; cy1[tid] = sy1[j];
        cx2[tid] = sx2[j]; cy2[tid] = sy2[j];
        car[tid] = sar[j]; ccl[tid] = scl[j]; ccf[tid] = sconf[j];
    }
    __syncthreads();

    unsigned long long word = 0;
    if (sconf[i] > 0.5f && j0 + 64 > i + 1) {      // row i valid
        float x1i = sx1[i], y1i = sy1[i], x2i = sx2[i], y2i = sy2[i];
        float ai = sar[i], ci = scl[i];
        for (int jj = 0; jj < 64; ++jj) {
            int j = j0 + jj;
            if (j <= i) continue;
            if (ccf[jj] <= 0.5f) continue;         // col j invalid (== j >= V)
            if (ccl[jj] != ci) continue;
            float iw = fminf(x2i, cx2[jj]) - fmaxf(x1i, cx1[jj]);
            iw = fmaxf(iw, 0.0f);
            float ih = fminf(y2i, cy2[jj]) - fmaxf(y1i, cy1[jj]);
            ih = fmaxf(ih, 0.0f);
            float inter = iw * ih;
            float denom = ai + car[jj] - inter + 1e-6f;   // ((ai+aj)-inter)+eps, L-to-R
            if (inter / denom >= 0.5f) word |= (1ull << jj);
        }
    }

    // wave-aggregated edge emission
    int pc = __popcll(word);
    int scan = pc;
    #pragma unroll
    for (int d = 1; d < 64; d <<= 1) {
        int t = __shfl_up(scan, d, 64);
        if (lane >= d) scan += t;
    }
    int total = __shfl(scan, 63, 64);
    if (total > 0) {
        unsigned int base = 0;
        if (lane == 63)
            base = atomicAdd((unsigned int*)(ws + ECNT_OFF), (unsigned int)total);
        base = (unsigned int)__shfl((int)base, 63, 64);
        unsigned int off = base + (unsigned int)(scan - pc);   // exclusive prefix
        unsigned int* edges = (unsigned int*)(ws + EDGE_OFF);
        unsigned long long t = word;
        while (t) {
            int bit = __builtin_ctzll(t);
            t &= t - 1ull;
            edges[off++] = ((unsigned int)i << 13) | (unsigned int)(j0 + bit);
        }
    }
}

// ---------------- NMS: segmented forward Gauss-Seidel + fused output ----------------
// Edges always point forward in rank (i<j), so processing 512-row segments in
// ascending order resolves cross-segment chains in ONE sweep; within a segment
// Jacobi iterates only to intra-segment chain depth (~2-4), with suppInt
// recomputed fresh each sweep (un-suppression stays correct). suppExt holds
// finalized earlier-segment suppressions (frozen during segment iterations).
// Each thread caches its <=16 edges in REGISTERS (E <= ECAP; else plain-Jacobi
// global fallback). Iteration count collapses vs whole-graph Jacobi.
__global__ __launch_bounds__(1024, 1) void nms_out_kernel(unsigned char* __restrict__ ws,
                                                          float* __restrict__ out) {
    int tid  = threadIdx.x;
    int lane = tid & 63;
    unsigned int E = *(const unsigned int*)(ws + ECNT_OFF);
    const unsigned int* gedges = (const unsigned int*)(ws + EDGE_OFF);
    const float* sconf = (const float*)(ws + SB(4));

    __shared__ unsigned long long valid[128], alive[128], suppExt[128], suppInt[SEGW];
    __shared__ int flag;

    for (int c = tid >> 6; c < 128; c += 16) {     // valid bitmap from sorted conf
        unsigned long long m = __ballot(sconf[(c << 6) + lane] > 0.5f);
        if (lane == 0) valid[c] = m;
    }
    if (tid < 128) suppExt[tid] = 0ull;
    __syncthreads();
    if (tid < 128) alive[tid] = valid[tid];
    __syncthreads();

    if (E <= (unsigned int)ECAP) {
        // ---- fast path: register-cached edges, segmented forward sweep ----
        unsigned int eu[ECAP / 1024];              // 16 regs
        int ne = 0;
        for (unsigned int e = tid; e < E; e += 1024) eu[ne++] = gedges[e];

        for (int s = 0; s < NSEG; ++s) {
            // skip segments with no valid rows (block-uniform LDS test)
            bool segv = false;
            #pragma unroll
            for (int k = 0; k < SEGW; ++k) segv |= (valid[s * SEGW + k] != 0ull);
            if (!segv) continue;

            for (;;) {                              // intra-segment Jacobi
                if (tid < SEGW) suppInt[tid] = 0ull;
                if (tid == 0) flag = 0;
                __syncthreads();
                for (int k = 0; k < ne; ++k) {
                    unsigned int u = eu[k];
                    unsigned int i = u >> 13, j = u & 8191u;
                    if ((int)(i >> 9) == s && (int)(j >> 9) == s &&
                        ((alive[i >> 6] >> (i & 63)) & 1ull))
                        atomicOr(&suppInt[(j >> 6) - s * SEGW], 1ull << (j & 63));
                }
                __syncthreads();
                if (tid < SEGW) {
                    int w = s * SEGW + tid;
                    unsigned long long na = valid[w] & ~suppExt[w] & ~suppInt[tid];
                    if (na != alive[w]) { alive[w] = na; flag = 1; }
                }
                __syncthreads();
                if (!flag) break;
            }
            // scatter finalized alive rows' cross-segment edges into suppExt
            for (int k = 0; k < ne; ++k) {
                unsigned int u = eu[k];
                unsigned int i = u >> 13, j = u & 8191u;
                if ((int)(i >> 9) == s && (int)(j >> 9) > s &&
                    ((alive[i >> 6] >> (i & 63)) & 1ull))
                    atomicOr(&suppExt[j >> 6], 1ull << (j & 63));
            }
            __syncthreads();
            if (tid < 128) {                        // pre-apply ext supp to later segs
                int w = tid;
                if ((w >> 3) > s) alive[w] = valid[w] & ~suppExt[w];
            }
            __syncthreads();
        }
    } else {
        // ---- fallback: plain whole-graph Jacobi from global (always correct) ----
        __shared__ unsigned long long supp[128];
        for (;;) {
            if (tid < 128) supp[tid] = 0ull;
            if (tid == 0) flag = 0;
            __syncthreads();
            for (unsigned int e = tid; e < E; e += 1024) {
                unsigned int u = gedges[e];
                unsigned int i = u >> 13, j = u & 8191u;
                if ((alive[i >> 6] >> (i & 63)) & 1ull)
                    atomicOr(&supp[j >> 6], 1ull << (j & 63));
            }
            __syncthreads();
            if (tid < 128) {
                unsigned long long na = valid[tid] & ~supp[tid];
                if (na != alive[tid]) { alive[tid] = na; flag = 1; }
            }
            __syncthreads();
            if (!flag) break;
        }
    }

    // ---- fused output: kept ranks get sorted box values, else zero ----
    for (int r = tid; r < NBOX; r += 1024) {
        bool keep = (alive[r >> 6] >> (r & 63)) & 1ull;
        float o0 = 0.f, o1 = 0.f, o2 = 0.f, o3 = 0.f, o4 = 0.f, o5 = 0.f;
        if (keep) {
            o0 = ((const float*)(ws + SB(0)))[r];
            o1 = ((const float*)(ws + SB(1)))[r];
            o2 = ((const float*)(ws + SB(2)))[r];
            o3 = ((const float*)(ws + SB(3)))[r];
            o4 = ((const float*)(ws + SB(4)))[r];
            o5 = ((const float*)(ws + SB(5)))[r];
        }
        out[r * 6 + 0] = o0;
        out[r * 6 + 1] = o1;
        out[r * 6 + 2] = o2;
        out[r * 6 + 3] = o3;
        out[r * 6 + 4] = o4;
        out[r * 6 + 5] = o5;
    }
}

extern "C" void kernel_launch(void* const* d_in, const int* in_sizes, int n_in,
                              void* d_out, int out_size, void* d_ws, size_t ws_size,
                              hipStream_t stream) {
    const float* x       = (const float*)d_in[0];
    const float* anchors = (const float*)d_in[1];
    float* out           = (float*)d_out;
    unsigned char* ws    = (unsigned char*)d_ws;

    sort_decode_kernel<<<NPAD / 64, 512, 0, stream>>>(x, anchors, ws);
    dim3 mgrid(128, NPAD / 256);
    mask_kernel<<<mgrid, 256, 0, stream>>>(ws);
    nms_out_kernel<<<1, 1024, 0, stream>>>(ws, out);
}